// Round 17
// baseline (195.901 us; speedup 1.0000x reference)
//
#include <hip/hip_runtime.h>

#define H 4
#define D1 128
#define D2 256
#define CIN 16
#define SLOPE 0.2f
#define LOG2E 1.4426950408889634f

typedef short short8v __attribute__((ext_vector_type(8)));
typedef float float4v __attribute__((ext_vector_type(4)));
typedef float float2v __attribute__((ext_vector_type(2)));
typedef __fp16 half2v __attribute__((ext_vector_type(2)));

__device__ __forceinline__ unsigned short f2bf(float f) {
    unsigned int u = __float_as_uint(f);
    u += 0x7FFFu + ((u >> 16) & 1u);
    return (unsigned short)(u >> 16);
}
__device__ __forceinline__ half2v pkrtz(float a, float b) {
    return __builtin_amdgcn_cvt_pkrtz(a, b);
}
__device__ __forceinline__ half2v h2_from_u32(unsigned u) {
    return __builtin_bit_cast(half2v, u);
}
__device__ __forceinline__ unsigned u32_from_h2(half2v h) {
    return __builtin_bit_cast(unsigned, h);
}
__device__ __forceinline__ unsigned short f2fp8x2(float a, float b) {
    return (unsigned short)__builtin_amdgcn_cvt_pk_fp8_f32(a, b, 0, false);
}
template<bool HI>
__device__ __forceinline__ half2v fp8x2_to_h2(unsigned u) {
#if __has_builtin(__builtin_amdgcn_cvt_scalef32_pk_f16_fp8)
    return __builtin_amdgcn_cvt_scalef32_pk_f16_fp8(u, 1.f, HI);
#else
    float2v f = __builtin_amdgcn_cvt_pk_f32_fp8(u, HI);
    return pkrtz(f.x, f.y);
#endif
}
__device__ __forceinline__ float fdot2(half2v a, half2v b, float c) {
#if __has_builtin(__builtin_amdgcn_fdot2)
    return __builtin_amdgcn_fdot2(a, b, c, false);
#else
    return c + (float)a.x * (float)b.x + (float)a.y * (float)b.y;
#endif
}
__device__ __forceinline__ int rfl(int v) {
    return __builtin_amdgcn_readfirstlane(v);
}
// 4-lane (quad) sum via DPP: xor1, xor2
__device__ __forceinline__ float dpp_sum4(float x) {
    float t;
    t = __int_as_float(__builtin_amdgcn_mov_dpp(__float_as_int(x), 0xB1, 0xF, 0xF, true));
    x += t;
    t = __int_as_float(__builtin_amdgcn_mov_dpp(__float_as_int(x), 0x4E, 0xF, 0xF, true));
    x += t;
    return x;
}
// add lane^XOR partner's packed-f16 pair
template<int XOR>
__device__ __forceinline__ half2v h2_xor_add(half2v v) {
    unsigned u = u32_from_h2(v);
    unsigned o = (unsigned)__shfl_xor((int)u, XOR);
    return v + h2_from_u32(o);
}

// ============ CSR build ============
__global__ void k_hist(const int* __restrict__ ei, int E, int ET,
                       int* __restrict__ deg) {
    int idx = blockIdx.x * blockDim.x + threadIdx.x;
    if (idx >= ET) return;
    int dst = (idx < E) ? ei[E + idx] : idx - E;
    atomicAdd(&deg[dst], 1);
}

__global__ __launch_bounds__(1024) void k_scan_one(
        const int* __restrict__ deg, int* __restrict__ rp,
        int* __restrict__ cur, int* __restrict__ ord, int n) {
    __shared__ int wsum[16];
    __shared__ int dh[256];
    int t = threadIdx.x;
    int lane = t & 63, w = t >> 6;
    if (t < 256) dh[t] = 0;
    int base = t * 32;
    int vals[32];
    const int4* dp = (const int4*)deg;
#pragma unroll
    for (int q = 0; q < 8; ++q) {
        int4 v = dp[(base >> 2) + q];
        vals[4 * q + 0] = v.x; vals[4 * q + 1] = v.y;
        vals[4 * q + 2] = v.z; vals[4 * q + 3] = v.w;
    }
    int loc[32];
    int s = 0;
#pragma unroll
    for (int k = 0; k < 32; ++k) {
        int idx = base + k;
        int v = (idx < n) ? vals[k] : 0;
        loc[k] = s;
        s += v;
    }
    int inc = s;
#pragma unroll
    for (int off = 1; off < 64; off <<= 1) {
        int u = __shfl_up(inc, off, 64);
        if (lane >= off) inc += u;
    }
    int excl = inc - s;
    if (lane == 63) wsum[w] = inc;
    __syncthreads();
    if (w == 0) {
        int v = (lane < 16) ? wsum[lane] : 0;
        int winc = v;
#pragma unroll
        for (int off = 1; off < 16; off <<= 1) {
            int u = __shfl_up(winc, off, 64);
            if (lane >= off) winc += u;
        }
        if (lane < 16) wsum[lane] = winc - v;
    }
    __syncthreads();
    int offw = wsum[w] + excl;
#pragma unroll
    for (int q = 0; q < 8; ++q) {
        int i0 = base + 4 * q;
        if (i0 + 3 < n) {
            *(int4*)(rp + i0) = make_int4(offw + loc[4 * q + 0], offw + loc[4 * q + 1],
                                          offw + loc[4 * q + 2], offw + loc[4 * q + 3]);
            *(int4*)(cur + i0) = make_int4(0, 0, 0, 0);
        } else {
#pragma unroll
            for (int e = 0; e < 4; ++e) {
                int idx = i0 + e;
                if (idx < n) { rp[idx] = offw + loc[4 * q + e]; cur[idx] = 0; }
            }
        }
    }
    // ---- counting sort by descending degree ----
#pragma unroll
    for (int k = 0; k < 32; ++k) {
        int idx = base + k;
        if (idx < n) {
            int bin = 255 - min(vals[k], 255);
            atomicAdd(&dh[bin], 1);
        }
    }
    __syncthreads();
    if (t < 64) {
        int b0 = dh[4 * t], b1 = dh[4 * t + 1], b2 = dh[4 * t + 2], b3 = dh[4 * t + 3];
        int s4 = b0 + b1 + b2 + b3;
        int inc2 = s4;
#pragma unroll
        for (int off = 1; off < 64; off <<= 1) {
            int u = __shfl_up(inc2, off, 64);
            if (lane >= off) inc2 += u;
        }
        int ex = inc2 - s4;
        dh[4 * t] = ex; dh[4 * t + 1] = ex + b0;
        dh[4 * t + 2] = ex + b0 + b1; dh[4 * t + 3] = ex + b0 + b1 + b2;
    }
    __syncthreads();
#pragma unroll
    for (int k = 0; k < 32; ++k) {
        int idx = base + k;
        if (idx < n) {
            int bin = 255 - min(vals[k], 255);
            int pos = atomicAdd(&dh[bin], 1);
            ord[pos] = idx;
        }
    }
}

__global__ void k_fill(const int* __restrict__ ei, int E, int ET,
                       const int* __restrict__ rp, int* __restrict__ cur,
                       int* __restrict__ eord) {
    int idx = blockIdx.x * blockDim.x + threadIdx.x;
    if (idx >= ET) return;
    int src, dst;
    if (idx < E) { src = ei[idx]; dst = ei[E + idx]; }
    else         { src = dst = idx - E; }
    int pos = atomicAdd(&cur[dst], 1);
    eord[rp[dst] + pos] = src;
}

// ============ fused prep: lin1 (xl fp8, xr f16) | W2 cvt | zero deg ========
__global__ __launch_bounds__(256) void k_prep(
        const float* __restrict__ x, const float* __restrict__ lb,
        const float* __restrict__ ub,
        const float* __restrict__ Wl, const float* __restrict__ bl,
        const float* __restrict__ Wr, const float* __restrict__ br,
        unsigned char* __restrict__ xl8, unsigned short* __restrict__ xr16,
        const float* __restrict__ W2l, const float* __restrict__ W2r,
        unsigned short* __restrict__ W2t,
        int* __restrict__ deg, int n, int B1) {
    __shared__ float Wls[CIN][D1];
    __shared__ float Wrs[CIN][D1];
    __shared__ float ys[16][CIN];
    int b = blockIdx.x;
    int t = threadIdx.x;
    if (b >= B1) {
        int rb = b - B1;
        if (rb < 256) {
            int idx = rb * 256 + t;
            int k = idx >> 9, c = idx & 511;
            float v = (c < 256) ? W2l[k * 256 + c] : W2r[k * 256 + (c - 256)];
            W2t[(size_t)c * 128 + k] = f2bf(v);
        } else {
            int idx = (rb - 256) * 256 + t;
            if (idx < n) deg[idx] = 0;
        }
        return;
    }
    int i0 = b * 16;
#pragma unroll
    for (int i = 0; i < 8; ++i) {
        int flat = t + 256 * i;
        int k = flat >> 7, c = flat & 127;
        Wls[k][c] = Wl[k * D1 + c];
        Wrs[k][c] = Wr[k * D1 + c];
    }
    {
        int node = t >> 4, k = t & 15;
        int gi = i0 + node;
        float xv = (gi < n) ? x[(size_t)gi * CIN + k] : 0.f;
        ys[node][k] = (xv - lb[k]) / (ub[k] - lb[k]);
    }
    __syncthreads();
    int c = t & 127;
    bool left = t < 128;
    const float (*Ws)[D1] = left ? Wls : Wrs;
    float bias = left ? bl[c] : br[c];
    for (int j = 0; j < 16; ++j) {
        float acc = bias;
#pragma unroll
        for (int k = 0; k < CIN; ++k) acc += ys[j][k] * Ws[k][c];
        int gi = i0 + j;
        float other = __shfl_xor(acc, 1);
        if (gi < n && !(c & 1)) {
            if (left)
                *(unsigned short*)(xl8 + (size_t)gi * D1 + c) = f2fp8x2(acc, other);
            else
                *(unsigned*)(xr16 + (size_t)gi * D1 + c) = u32_from_h2(pkrtz(acc, other));
        }
    }
}

// ============ layer-2 linear: bf16 MFMA GEMM; xl2 fp8, xr2 f16 ============
__global__ __launch_bounds__(256) void k_lin2_mfma(
        const unsigned short* __restrict__ h1b,
        const unsigned short* __restrict__ W2t,
        const float* __restrict__ b2l, const float* __restrict__ b2r,
        unsigned char* __restrict__ xl2,
        unsigned short* __restrict__ xr2,
        int n) {
    __shared__ unsigned short At[128 * 128];
    __shared__ unsigned short Bt[128 * 128];
    int t = threadIdx.x;
    int row0 = blockIdx.x * 128;
    int col0 = blockIdx.y * 128;

    {
        int r = t >> 1, hh = (t & 1) * 64;
        bool ok = (row0 + r) < n;
        const unsigned short* gA = h1b + (size_t)(row0 + r) * 128 + hh;
        const unsigned short* gB = W2t + (size_t)(col0 + r) * 128 + hh;
#pragma unroll
        for (int i = 0; i < 8; ++i) {
            uint4 vA = ok ? *(const uint4*)(gA + i * 8) : make_uint4(0, 0, 0, 0);
            uint4 vB = *(const uint4*)(gB + i * 8);
            int col = hh + i * 8;
            int idx = (r * 128 + col) ^ ((r & 15) << 3);
            *(uint4*)&At[idx] = vA;
            *(uint4*)&Bt[idx] = vB;
        }
    }
    __syncthreads();

    int w = t >> 6, l = t & 63;
    int wr = w >> 1, wc = w & 1;
    float4v acc[4][4];
#pragma unroll
    for (int m = 0; m < 4; ++m)
#pragma unroll
        for (int nn = 0; nn < 4; ++nn) acc[m][nn] = (float4v)0.f;

#pragma unroll
    for (int ks = 0; ks < 4; ++ks) {
        int kb = ks * 32 + ((l >> 4) << 3);
        short8v a[4], b[4];
#pragma unroll
        for (int m = 0; m < 4; ++m) {
            int r = wr * 64 + m * 16 + (l & 15);
            a[m] = *(const short8v*)&At[(r * 128 + kb) ^ ((r & 15) << 3)];
        }
#pragma unroll
        for (int nn = 0; nn < 4; ++nn) {
            int c = wc * 64 + nn * 16 + (l & 15);
            b[nn] = *(const short8v*)&Bt[(c * 128 + kb) ^ ((c & 15) << 3)];
        }
#pragma unroll
        for (int m = 0; m < 4; ++m)
#pragma unroll
            for (int nn = 0; nn < 4; ++nn)
                acc[m][nn] = __builtin_amdgcn_mfma_f32_16x16x32_bf16(
                    a[m], b[nn], acc[m][nn], 0, 0, 0);
    }

    if (col0 < 256) {
        const float* bp = b2l;
        int cb = col0;
#pragma unroll
        for (int nn = 0; nn < 4; ++nn) {
            int colc = cb + wc * 64 + nn * 16 + (l & 15);
            float bv = bp[colc];
#pragma unroll
            for (int m = 0; m < 4; ++m) {
                int rbase = row0 + wr * 64 + m * 16 + ((l >> 4) << 2);
#pragma unroll
                for (int r = 0; r < 4; ++r) {
                    int row = rbase + r;
                    float val = acc[m][nn][r] + bv;
                    float other = __shfl_xor(val, 1);
                    if (!(l & 1) && row < n)
                        *(unsigned short*)(xl2 + (size_t)row * 256 + colc) =
                            f2fp8x2(val, other);
                }
            }
        }
    } else {
        const float* bp = b2r;
        int cb = col0 - 256;
#pragma unroll
        for (int nn = 0; nn < 4; ++nn) {
            int colc = cb + wc * 64 + nn * 16 + (l & 15);
            float bv = bp[colc];
#pragma unroll
            for (int m = 0; m < 4; ++m) {
                int rbase = row0 + wr * 64 + m * 16 + ((l >> 4) << 2);
#pragma unroll
                for (int r = 0; r < 4; ++r) {
                    int row = rbase + r;
                    float val = acc[m][nn][r] + bv;
                    float other = __shfl_xor(val, 1);
                    if (!(l & 1) && row < n)
                        *(unsigned*)(xr2 + (size_t)row * 256 + colc) =
                            u32_from_h2(pkrtz(val, other));
                }
            }
        }
    }
}

// ============ layer-1 aggregation: edge-per-group layout ============
// wave = node; 4 groups x 16 lanes; lane p: comps [8p,8p+8) (uint2 fp8 row);
// head = quad (32 comps = 4 lanes); quad DPP reduce; live-mask tail.
__global__ __launch_bounds__(256) void k_agg1(
        const unsigned char* __restrict__ xl8, const unsigned short* __restrict__ xr16,
        const float* __restrict__ att, const float* __restrict__ bias,
        const int* __restrict__ rp, const int* __restrict__ deg,
        const int* __restrict__ eord, const int* __restrict__ ord,
        unsigned short* __restrict__ h1b, int n) {
    int t = threadIdx.x;
    int node0 = blockIdx.x * 4 + (t >> 6);
    int l = t & 63, g = l >> 4, p = l & 15;
    bool valid = node0 < n;
    int node = rfl(ord[valid ? node0 : n - 1]);
    // xr comps [8p, 8p+8) : 8 f16 = uint4
    uint4 xq = *(const uint4*)(xr16 + (size_t)node * 128 + p * 8);
    half2v xr0 = h2_from_u32(xq.x), xr1 = h2_from_u32(xq.y);
    half2v xr2_ = h2_from_u32(xq.z), xr3 = h2_from_u32(xq.w);
    const float4* avp = (const float4*)(att + p * 8);
    float4 af0 = avp[0], af1 = avp[1];
    half2v av0 = pkrtz(af0.x * LOG2E, af0.y * LOG2E);
    half2v av1 = pkrtz(af0.z * LOG2E, af0.w * LOG2E);
    half2v av2 = pkrtz(af1.x * LOG2E, af1.y * LOG2E);
    half2v av3 = pkrtz(af1.z * LOG2E, af1.w * LOG2E);
    half2v slp = pkrtz(SLOPE, SLOPE);
    int start = rfl(rp[node]);
    int cnt = valid ? deg[node] : 0;
    cnt = rfl(cnt);
    float d = 0.f;
    half2v a0 = pkrtz(0.f, 0.f), a1 = a0, a2 = a0, a3 = a0;
    int cntR = (cnt + 3) & ~3;
    int ecl = cnt - 1;
    uint2 row;
    if (cntR > 0) {
        int src = eord[start + min(g, ecl)];
        row = *(const uint2*)(xl8 + ((unsigned)src << 7) + p * 8);
    }
    for (int j = 0; j < cntR; j += 4) {
        uint2 cr = row;
        bool live = (j + g) <= ecl;
        int jn = j + 4;
        if (jn < cntR) {
            int src = eord[start + min(jn + g, ecl)];
            row = *(const uint2*)(xl8 + ((unsigned)src << 7) + p * 8);
        }
        half2v x0 = fp8x2_to_h2<false>(cr.x), x1 = fp8x2_to_h2<true>(cr.x);
        half2v x2 = fp8x2_to_h2<false>(cr.y), x3 = fp8x2_to_h2<true>(cr.y);
        half2v s;
        float lg = 0.f;
        s = x0 + xr0;  s = __builtin_elementwise_max(s, s * slp); lg = fdot2(av0, s, lg);
        s = x1 + xr1;  s = __builtin_elementwise_max(s, s * slp); lg = fdot2(av1, s, lg);
        s = x2 + xr2_; s = __builtin_elementwise_max(s, s * slp); lg = fdot2(av2, s, lg);
        s = x3 + xr3;  s = __builtin_elementwise_max(s, s * slp); lg = fdot2(av3, s, lg);
        lg = dpp_sum4(lg);
        float e = exp2f(lg);
        e = live ? e : 0.f;
        d += e;
        half2v ep = pkrtz(e, e);
        a0 += ep * x0; a1 += ep * x1; a2 += ep * x2; a3 += ep * x3;
    }
    // cross-group reduce
    d += __shfl_xor(d, 16); d += __shfl_xor(d, 32);
    a0 = h2_xor_add<16>(a0); a0 = h2_xor_add<32>(a0);
    a1 = h2_xor_add<16>(a1); a1 = h2_xor_add<32>(a1);
    a2 = h2_xor_add<16>(a2); a2 = h2_xor_add<32>(a2);
    a3 = h2_xor_add<16>(a3); a3 = h2_xor_add<32>(a3);
    if (valid && l < 16) {
        float inv = 1.f / d;
        const float4* bp = (const float4*)(bias + p * 8);
        float4 b0 = bp[0], b1 = bp[1];
        float o0 = fmaxf((float)a0.x * inv + b0.x, 0.f);
        float o1 = fmaxf((float)a0.y * inv + b0.y, 0.f);
        float o2 = fmaxf((float)a1.x * inv + b0.z, 0.f);
        float o3 = fmaxf((float)a1.y * inv + b0.w, 0.f);
        float o4 = fmaxf((float)a2.x * inv + b1.x, 0.f);
        float o5 = fmaxf((float)a2.y * inv + b1.y, 0.f);
        float o6 = fmaxf((float)a3.x * inv + b1.z, 0.f);
        float o7 = fmaxf((float)a3.y * inv + b1.w, 0.f);
        uint4 o;
        o.x = ((unsigned)f2bf(o1) << 16) | f2bf(o0);
        o.y = ((unsigned)f2bf(o3) << 16) | f2bf(o2);
        o.z = ((unsigned)f2bf(o5) << 16) | f2bf(o4);
        o.w = ((unsigned)f2bf(o7) << 16) | f2bf(o6);
        *(uint4*)(h1b + (size_t)node * 128 + p * 8) = o;
    }
}

// ============ layer-2 aggregation + head: edge-per-group layout ============
// lane p: comps [16p,16p+16) (uint4 fp8 row); head = quad.
__global__ __launch_bounds__(256) void k_agg2(
        const unsigned char* __restrict__ xl8, const unsigned short* __restrict__ xr16,
        const float* __restrict__ att, const float* __restrict__ b2,
        const float* __restrict__ W3, const float* __restrict__ b3,
        const int* __restrict__ rp, const int* __restrict__ deg,
        const int* __restrict__ eord, const int* __restrict__ ord,
        float* __restrict__ out, int n) {
    int t = threadIdx.x;
    int node0 = blockIdx.x * 4 + (t >> 6);
    int l = t & 63, g = l >> 4, p = l & 15;
    bool valid = node0 < n;
    int node = rfl(ord[valid ? node0 : n - 1]);
    // xr comps [16p,16p+16): 16 f16 = 2x uint4
    const uint4* xrq = (const uint4*)(xr16 + (size_t)node * 256 + p * 16);
    uint4 xa = xrq[0], xb = xrq[1];
    half2v xr0 = h2_from_u32(xa.x), xr1 = h2_from_u32(xa.y);
    half2v xr2_ = h2_from_u32(xa.z), xr3 = h2_from_u32(xa.w);
    half2v xr4 = h2_from_u32(xb.x), xr5 = h2_from_u32(xb.y);
    half2v xr6 = h2_from_u32(xb.z), xr7 = h2_from_u32(xb.w);
    const float4* avp = (const float4*)(att + p * 16);
    float4 af0 = avp[0], af1 = avp[1], af2 = avp[2], af3 = avp[3];
    half2v av0 = pkrtz(af0.x * LOG2E, af0.y * LOG2E);
    half2v av1 = pkrtz(af0.z * LOG2E, af0.w * LOG2E);
    half2v av2 = pkrtz(af1.x * LOG2E, af1.y * LOG2E);
    half2v av3 = pkrtz(af1.z * LOG2E, af1.w * LOG2E);
    half2v av4 = pkrtz(af2.x * LOG2E, af2.y * LOG2E);
    half2v av5 = pkrtz(af2.z * LOG2E, af2.w * LOG2E);
    half2v av6 = pkrtz(af3.x * LOG2E, af3.y * LOG2E);
    half2v av7 = pkrtz(af3.z * LOG2E, af3.w * LOG2E);
    half2v slp = pkrtz(SLOPE, SLOPE);
    int start = rfl(rp[node]);
    int cnt = valid ? deg[node] : 0;
    cnt = rfl(cnt);
    float d = 0.f;
    half2v a0 = pkrtz(0.f, 0.f), a1 = a0, a2 = a0, a3 = a0;
    half2v a4 = a0, a5 = a0, a6 = a0, a7 = a0;
    int cntR = (cnt + 3) & ~3;
    int ecl = cnt - 1;
    uint4 row;
    if (cntR > 0) {
        int src = eord[start + min(g, ecl)];
        row = *(const uint4*)(xl8 + ((unsigned)src << 8) + p * 16);
    }
    for (int j = 0; j < cntR; j += 4) {
        uint4 cr = row;
        bool live = (j + g) <= ecl;
        int jn = j + 4;
        if (jn < cntR) {
            int src = eord[start + min(jn + g, ecl)];
            row = *(const uint4*)(xl8 + ((unsigned)src << 8) + p * 16);
        }
        half2v x0 = fp8x2_to_h2<false>(cr.x), x1 = fp8x2_to_h2<true>(cr.x);
        half2v x2 = fp8x2_to_h2<false>(cr.y), x3 = fp8x2_to_h2<true>(cr.y);
        half2v x4 = fp8x2_to_h2<false>(cr.z), x5 = fp8x2_to_h2<true>(cr.z);
        half2v x6 = fp8x2_to_h2<false>(cr.w), x7 = fp8x2_to_h2<true>(cr.w);
        half2v s;
        float lg = 0.f;
        s = x0 + xr0;  s = __builtin_elementwise_max(s, s * slp); lg = fdot2(av0, s, lg);
        s = x1 + xr1;  s = __builtin_elementwise_max(s, s * slp); lg = fdot2(av1, s, lg);
        s = x2 + xr2_; s = __builtin_elementwise_max(s, s * slp); lg = fdot2(av2, s, lg);
        s = x3 + xr3;  s = __builtin_elementwise_max(s, s * slp); lg = fdot2(av3, s, lg);
        s = x4 + xr4;  s = __builtin_elementwise_max(s, s * slp); lg = fdot2(av4, s, lg);
        s = x5 + xr5;  s = __builtin_elementwise_max(s, s * slp); lg = fdot2(av5, s, lg);
        s = x6 + xr6;  s = __builtin_elementwise_max(s, s * slp); lg = fdot2(av6, s, lg);
        s = x7 + xr7;  s = __builtin_elementwise_max(s, s * slp); lg = fdot2(av7, s, lg);
        lg = dpp_sum4(lg);
        float e = exp2f(lg);
        e = live ? e : 0.f;
        d += e;
        half2v ep = pkrtz(e, e);
        a0 += ep * x0; a1 += ep * x1; a2 += ep * x2; a3 += ep * x3;
        a4 += ep * x4; a5 += ep * x5; a6 += ep * x6; a7 += ep * x7;
    }
    // cross-group reduce (sum the 4 groups' partials)
    d += __shfl_xor(d, 16); d += __shfl_xor(d, 32);
    a0 = h2_xor_add<16>(a0); a0 = h2_xor_add<32>(a0);
    a1 = h2_xor_add<16>(a1); a1 = h2_xor_add<32>(a1);
    a2 = h2_xor_add<16>(a2); a2 = h2_xor_add<32>(a2);
    a3 = h2_xor_add<16>(a3); a3 = h2_xor_add<32>(a3);
    a4 = h2_xor_add<16>(a4); a4 = h2_xor_add<32>(a4);
    a5 = h2_xor_add<16>(a5); a5 = h2_xor_add<32>(a5);
    a6 = h2_xor_add<16>(a6); a6 = h2_xor_add<32>(a6);
    a7 = h2_xor_add<16>(a7); a7 = h2_xor_add<32>(a7);
    // head mean: lanes p, p^4, p^8, p^12 hold same within-head offset
    a0 = h2_xor_add<4>(a0); a0 = h2_xor_add<8>(a0);
    a1 = h2_xor_add<4>(a1); a1 = h2_xor_add<8>(a1);
    a2 = h2_xor_add<4>(a2); a2 = h2_xor_add<8>(a2);
    a3 = h2_xor_add<4>(a3); a3 = h2_xor_add<8>(a3);
    a4 = h2_xor_add<4>(a4); a4 = h2_xor_add<8>(a4);
    a5 = h2_xor_add<4>(a5); a5 = h2_xor_add<8>(a5);
    a6 = h2_xor_add<4>(a6); a6 = h2_xor_add<8>(a6);
    a7 = h2_xor_add<4>(a7); a7 = h2_xor_add<8>(a7);
    float inv = 0.25f / d;
    int q4 = p & 3;                 // lane holds mean comps [16*q4, 16*q4+16)
    float m[16];
    m[0]  = (float)a0.x * inv; m[1]  = (float)a0.y * inv;
    m[2]  = (float)a1.x * inv; m[3]  = (float)a1.y * inv;
    m[4]  = (float)a2.x * inv; m[5]  = (float)a2.y * inv;
    m[6]  = (float)a3.x * inv; m[7]  = (float)a3.y * inv;
    m[8]  = (float)a4.x * inv; m[9]  = (float)a4.y * inv;
    m[10] = (float)a5.x * inv; m[11] = (float)a5.y * inv;
    m[12] = (float)a6.x * inv; m[13] = (float)a6.y * inv;
    m[14] = (float)a7.x * inv; m[15] = (float)a7.y * inv;
    int c0 = 16 * q4;
    float p0 = 0.f, p1 = 0.f, p2 = 0.f, p3 = 0.f, p4 = 0.f;
#pragma unroll
    for (int k = 0; k < 16; ++k) {
        float v = fmaxf(m[k] + b2[c0 + k], 0.f);
        const float* wrow = W3 + (c0 + k) * 5;
        p0 += v * wrow[0]; p1 += v * wrow[1]; p2 += v * wrow[2];
        p3 += v * wrow[3]; p4 += v * wrow[4];
    }
    p0 = dpp_sum4(p0); p1 = dpp_sum4(p1); p2 = dpp_sum4(p2);
    p3 = dpp_sum4(p3); p4 = dpp_sum4(p4);
    if (l == 0 && valid) {
        float* o = out + (size_t)node * 5;
        o[0] = 1.f / (1.f + __expf(-(p0 + b3[0])));
        o[1] = 1.f / (1.f + __expf(-(p1 + b3[1])));
        o[2] = 1.f / (1.f + __expf(-(p2 + b3[2])));
        o[3] = 1.f / (1.f + __expf(-(p3 + b3[3])));
        o[4] = 1.f / (1.f + __expf(-(p4 + b3[4])));
    }
}

extern "C" void kernel_launch(void* const* d_in, const int* in_sizes, int n_in,
                              void* d_out, int out_size, void* d_ws, size_t ws_size,
                              hipStream_t stream) {
    const float* x     = (const float*)d_in[0];
    const int*   ei    = (const int*)d_in[1];
    const float* lb    = (const float*)d_in[2];
    const float* ub    = (const float*)d_in[3];
    const float* W1l   = (const float*)d_in[4];
    const float* b1l   = (const float*)d_in[5];
    const float* W1r   = (const float*)d_in[6];
    const float* b1r   = (const float*)d_in[7];
    const float* att1  = (const float*)d_in[8];
    const float* bias1 = (const float*)d_in[9];
    const float* W2l   = (const float*)d_in[10];
    const float* b2l   = (const float*)d_in[11];
    const float* W2r   = (const float*)d_in[12];
    const float* b2r   = (const float*)d_in[13];
    const float* att2  = (const float*)d_in[14];
    const float* bias2 = (const float*)d_in[15];
    const float* W3    = (const float*)d_in[16];
    const float* b3    = (const float*)d_in[17];

    int n  = in_sizes[0] / CIN;
    int E  = in_sizes[1] / 2;
    int ET = E + n;

    char* ws = (char*)d_ws;
    size_t off = 0;
    auto alloc = [&](size_t nbytes) {
        void* p = ws + off;
        off += (nbytes + 255) & ~(size_t)255;
        return p;
    };
    unsigned char*  xl1 = (unsigned char*)alloc((size_t)n * D1);        // fp8
    unsigned short* xr1 = (unsigned short*)alloc((size_t)n * D1 * 2);   // f16
    unsigned short* h1b = (unsigned short*)alloc((size_t)n * D1 * 2);   // bf16
    unsigned char*  xl2 = (unsigned char*)alloc((size_t)n * D2);        // fp8
    unsigned short* xr2 = (unsigned short*)alloc((size_t)n * D2 * 2);   // f16
    unsigned short* W2t = (unsigned short*)alloc((size_t)512 * 128 * 2);
    int* deg  = (int*)alloc((size_t)n * 4 + 8192);  // pad: scan over-reads int4
    int* cur  = (int*)alloc((size_t)n * 4);
    int* rp   = (int*)alloc((size_t)n * 4);
    int* ord  = (int*)alloc((size_t)n * 4);
    int* eord = (int*)alloc((size_t)ET * 4 + 256);

    // ---- prep: lin1 + cvtW2 + zero deg (one launch) ----
    int B1 = (n + 15) / 16;
    int BZ = (n + 255) / 256;
    k_prep<<<B1 + 256 + BZ, 256, 0, stream>>>(
        x, lb, ub, W1l, b1l, W1r, b1r, xl1, xr1, W2l, W2r, W2t, deg, n, B1);

    // ---- CSR build + degree sort ----
    k_hist<<<(ET + 255) / 256, 256, 0, stream>>>(ei, E, ET, deg);
    k_scan_one<<<1, 1024, 0, stream>>>(deg, rp, cur, ord, n);
    k_fill<<<(ET + 255) / 256, 256, 0, stream>>>(ei, E, ET, rp, cur, eord);

    // ---- layer 1 aggregation ----
    k_agg1<<<(n + 3) / 4, 256, 0, stream>>>(xl1, xr1, att1, bias1, rp, deg,
                                            eord, ord, h1b, n);

    // ---- layer 2 ----
    dim3 g2((n + 127) / 128, 4);
    k_lin2_mfma<<<g2, 256, 0, stream>>>(h1b, W2t, b2l, b2r, xl2, xr2, n);
    k_agg2<<<(n + 3) / 4, 256, 0, stream>>>(xl2, xr2, att2, bias2, W3, b3,
                                            rp, deg, eord, ord, (float*)d_out, n);
}

// Round 18
// 166.474 us; speedup vs baseline: 1.1768x; 1.1768x over previous
//
#include <hip/hip_runtime.h>

#define H 4
#define D1 128
#define D2 256
#define CIN 16
#define SLOPE 0.2f
#define LOG2E 1.4426950408889634f

typedef short short8v __attribute__((ext_vector_type(8)));
typedef float float4v __attribute__((ext_vector_type(4)));
typedef float float2v __attribute__((ext_vector_type(2)));
typedef __fp16 half2v __attribute__((ext_vector_type(2)));

__device__ __forceinline__ unsigned short f2bf(float f) {
    unsigned int u = __float_as_uint(f);
    u += 0x7FFFu + ((u >> 16) & 1u);
    return (unsigned short)(u >> 16);
}
__device__ __forceinline__ half2v pkrtz(float a, float b) {
    return __builtin_amdgcn_cvt_pkrtz(a, b);
}
__device__ __forceinline__ half2v h2_from_u32(unsigned u) {
    return __builtin_bit_cast(half2v, u);
}
__device__ __forceinline__ unsigned u32_from_h2(half2v h) {
    return __builtin_bit_cast(unsigned, h);
}
__device__ __forceinline__ unsigned short f2fp8x2(float a, float b) {
    return (unsigned short)__builtin_amdgcn_cvt_pk_fp8_f32(a, b, 0, false);
}
template<bool HI>
__device__ __forceinline__ half2v fp8x2_to_h2(unsigned u) {
#if __has_builtin(__builtin_amdgcn_cvt_scalef32_pk_f16_fp8)
    return __builtin_amdgcn_cvt_scalef32_pk_f16_fp8(u, 1.f, HI);
#else
    float2v f = __builtin_amdgcn_cvt_pk_f32_fp8(u, HI);
    return pkrtz(f.x, f.y);
#endif
}
__device__ __forceinline__ float fdot2(half2v a, half2v b, float c) {
#if __has_builtin(__builtin_amdgcn_fdot2)
    return __builtin_amdgcn_fdot2(a, b, c, false);
#else
    return c + (float)a.x * (float)b.x + (float)a.y * (float)b.y;
#endif
}
__device__ __forceinline__ int rfl(int v) {
    return __builtin_amdgcn_readfirstlane(v);
}

// ---- full-VALU 16-lane sum via DPP (f32) ----
__device__ __forceinline__ float dpp_sum16(float x) {
    float t;
    t = __int_as_float(__builtin_amdgcn_mov_dpp(__float_as_int(x), 0xB1, 0xF, 0xF, true));
    x += t;
    t = __int_as_float(__builtin_amdgcn_mov_dpp(__float_as_int(x), 0x4E, 0xF, 0xF, true));
    x += t;
    t = __int_as_float(__builtin_amdgcn_mov_dpp(__float_as_int(x), 0x141, 0xF, 0xF, true));
    x += t;
    t = __int_as_float(__builtin_amdgcn_mov_dpp(__float_as_int(x), 0x140, 0xF, 0xF, true));
    x += t;
    return x;
}
// ---- packed-f16 16-lane sum via DPP (2 independent reductions at once) ----
__device__ __forceinline__ half2v dpp_sum16_h2(half2v x) {
    unsigned t;
    t = (unsigned)__builtin_amdgcn_mov_dpp((int)u32_from_h2(x), 0xB1, 0xF, 0xF, true);
    x += h2_from_u32(t);
    t = (unsigned)__builtin_amdgcn_mov_dpp((int)u32_from_h2(x), 0x4E, 0xF, 0xF, true);
    x += h2_from_u32(t);
    t = (unsigned)__builtin_amdgcn_mov_dpp((int)u32_from_h2(x), 0x141, 0xF, 0xF, true);
    x += h2_from_u32(t);
    t = (unsigned)__builtin_amdgcn_mov_dpp((int)u32_from_h2(x), 0x140, 0xF, 0xF, true);
    x += h2_from_u32(t);
    return x;
}

// ============ CSR build ============
__global__ void k_hist(const int* __restrict__ ei, int E, int ET,
                       int* __restrict__ deg) {
    int idx = blockIdx.x * blockDim.x + threadIdx.x;
    if (idx >= ET) return;
    int dst = (idx < E) ? ei[E + idx] : idx - E;
    atomicAdd(&deg[dst], 1);
}

__global__ __launch_bounds__(1024) void k_scan_one(
        const int* __restrict__ deg, int* __restrict__ rp,
        int* __restrict__ cur, int* __restrict__ ord, int n) {
    __shared__ int wsum[16];
    __shared__ int dh[256];
    int t = threadIdx.x;
    int lane = t & 63, w = t >> 6;
    if (t < 256) dh[t] = 0;
    int base = t * 32;
    int vals[32];
    const int4* dp = (const int4*)deg;
#pragma unroll
    for (int q = 0; q < 8; ++q) {
        int4 v = dp[(base >> 2) + q];
        vals[4 * q + 0] = v.x; vals[4 * q + 1] = v.y;
        vals[4 * q + 2] = v.z; vals[4 * q + 3] = v.w;
    }
    int loc[32];
    int s = 0;
#pragma unroll
    for (int k = 0; k < 32; ++k) {
        int idx = base + k;
        int v = (idx < n) ? vals[k] : 0;
        loc[k] = s;
        s += v;
    }
    int inc = s;
#pragma unroll
    for (int off = 1; off < 64; off <<= 1) {
        int u = __shfl_up(inc, off, 64);
        if (lane >= off) inc += u;
    }
    int excl = inc - s;
    if (lane == 63) wsum[w] = inc;
    __syncthreads();
    if (w == 0) {
        int v = (lane < 16) ? wsum[lane] : 0;
        int winc = v;
#pragma unroll
        for (int off = 1; off < 16; off <<= 1) {
            int u = __shfl_up(winc, off, 64);
            if (lane >= off) winc += u;
        }
        if (lane < 16) wsum[lane] = winc - v;
    }
    __syncthreads();
    int offw = wsum[w] + excl;
#pragma unroll
    for (int q = 0; q < 8; ++q) {
        int i0 = base + 4 * q;
        if (i0 + 3 < n) {
            *(int4*)(rp + i0) = make_int4(offw + loc[4 * q + 0], offw + loc[4 * q + 1],
                                          offw + loc[4 * q + 2], offw + loc[4 * q + 3]);
            *(int4*)(cur + i0) = make_int4(0, 0, 0, 0);
        } else {
#pragma unroll
            for (int e = 0; e < 4; ++e) {
                int idx = i0 + e;
                if (idx < n) { rp[idx] = offw + loc[4 * q + e]; cur[idx] = 0; }
            }
        }
    }
    // ---- counting sort by descending degree ----
#pragma unroll
    for (int k = 0; k < 32; ++k) {
        int idx = base + k;
        if (idx < n) {
            int bin = 255 - min(vals[k], 255);
            atomicAdd(&dh[bin], 1);
        }
    }
    __syncthreads();
    if (t < 64) {
        int b0 = dh[4 * t], b1 = dh[4 * t + 1], b2 = dh[4 * t + 2], b3 = dh[4 * t + 3];
        int s4 = b0 + b1 + b2 + b3;
        int inc2 = s4;
#pragma unroll
        for (int off = 1; off < 64; off <<= 1) {
            int u = __shfl_up(inc2, off, 64);
            if (lane >= off) inc2 += u;
        }
        int ex = inc2 - s4;
        dh[4 * t] = ex; dh[4 * t + 1] = ex + b0;
        dh[4 * t + 2] = ex + b0 + b1; dh[4 * t + 3] = ex + b0 + b1 + b2;
    }
    __syncthreads();
#pragma unroll
    for (int k = 0; k < 32; ++k) {
        int idx = base + k;
        if (idx < n) {
            int bin = 255 - min(vals[k], 255);
            int pos = atomicAdd(&dh[bin], 1);
            ord[pos] = idx;
        }
    }
}

__global__ void k_fill(const int* __restrict__ ei, int E, int ET,
                       const int* __restrict__ rp, int* __restrict__ cur,
                       int* __restrict__ eord) {
    int idx = blockIdx.x * blockDim.x + threadIdx.x;
    if (idx >= ET) return;
    int src, dst;
    if (idx < E) { src = ei[idx]; dst = ei[E + idx]; }
    else         { src = dst = idx - E; }
    int pos = atomicAdd(&cur[dst], 1);
    eord[rp[dst] + pos] = src;
}

// ============ fused prep: lin1 (xl fp8, xr f16) | W2 cvt | zero deg ========
__global__ __launch_bounds__(256) void k_prep(
        const float* __restrict__ x, const float* __restrict__ lb,
        const float* __restrict__ ub,
        const float* __restrict__ Wl, const float* __restrict__ bl,
        const float* __restrict__ Wr, const float* __restrict__ br,
        unsigned char* __restrict__ xl8, unsigned short* __restrict__ xr16,
        const float* __restrict__ W2l, const float* __restrict__ W2r,
        unsigned short* __restrict__ W2t,
        int* __restrict__ deg, int n, int B1) {
    __shared__ float Wls[CIN][D1];
    __shared__ float Wrs[CIN][D1];
    __shared__ float ys[16][CIN];
    int b = blockIdx.x;
    int t = threadIdx.x;
    if (b >= B1) {
        int rb = b - B1;
        if (rb < 256) {
            int idx = rb * 256 + t;
            int k = idx >> 9, c = idx & 511;
            float v = (c < 256) ? W2l[k * 256 + c] : W2r[k * 256 + (c - 256)];
            W2t[(size_t)c * 128 + k] = f2bf(v);
        } else {
            int idx = (rb - 256) * 256 + t;
            if (idx < n) deg[idx] = 0;
        }
        return;
    }
    int i0 = b * 16;
#pragma unroll
    for (int i = 0; i < 8; ++i) {
        int flat = t + 256 * i;
        int k = flat >> 7, c = flat & 127;
        Wls[k][c] = Wl[k * D1 + c];
        Wrs[k][c] = Wr[k * D1 + c];
    }
    {
        int node = t >> 4, k = t & 15;
        int gi = i0 + node;
        float xv = (gi < n) ? x[(size_t)gi * CIN + k] : 0.f;
        ys[node][k] = (xv - lb[k]) / (ub[k] - lb[k]);
    }
    __syncthreads();
    int c = t & 127;
    bool left = t < 128;
    const float (*Ws)[D1] = left ? Wls : Wrs;
    float bias = left ? bl[c] : br[c];
    for (int j = 0; j < 16; ++j) {
        float acc = bias;
#pragma unroll
        for (int k = 0; k < CIN; ++k) acc += ys[j][k] * Ws[k][c];
        int gi = i0 + j;
        float other = __shfl_xor(acc, 1);
        if (gi < n && !(c & 1)) {
            if (left)
                *(unsigned short*)(xl8 + (size_t)gi * D1 + c) = f2fp8x2(acc, other);
            else
                *(unsigned*)(xr16 + (size_t)gi * D1 + c) = u32_from_h2(pkrtz(acc, other));
        }
    }
}

// ============ layer-2 linear: bf16 MFMA GEMM; xl2 fp8, xr2 f16 ============
__global__ __launch_bounds__(256) void k_lin2_mfma(
        const unsigned short* __restrict__ h1b,
        const unsigned short* __restrict__ W2t,
        const float* __restrict__ b2l, const float* __restrict__ b2r,
        unsigned char* __restrict__ xl2,
        unsigned short* __restrict__ xr2,
        int n) {
    __shared__ unsigned short At[128 * 128];
    __shared__ unsigned short Bt[128 * 128];
    int t = threadIdx.x;
    int row0 = blockIdx.x * 128;
    int col0 = blockIdx.y * 128;

    {
        int r = t >> 1, hh = (t & 1) * 64;
        bool ok = (row0 + r) < n;
        const unsigned short* gA = h1b + (size_t)(row0 + r) * 128 + hh;
        const unsigned short* gB = W2t + (size_t)(col0 + r) * 128 + hh;
#pragma unroll
        for (int i = 0; i < 8; ++i) {
            uint4 vA = ok ? *(const uint4*)(gA + i * 8) : make_uint4(0, 0, 0, 0);
            uint4 vB = *(const uint4*)(gB + i * 8);
            int col = hh + i * 8;
            int idx = (r * 128 + col) ^ ((r & 15) << 3);
            *(uint4*)&At[idx] = vA;
            *(uint4*)&Bt[idx] = vB;
        }
    }
    __syncthreads();

    int w = t >> 6, l = t & 63;
    int wr = w >> 1, wc = w & 1;
    float4v acc[4][4];
#pragma unroll
    for (int m = 0; m < 4; ++m)
#pragma unroll
        for (int nn = 0; nn < 4; ++nn) acc[m][nn] = (float4v)0.f;

#pragma unroll
    for (int ks = 0; ks < 4; ++ks) {
        int kb = ks * 32 + ((l >> 4) << 3);
        short8v a[4], b[4];
#pragma unroll
        for (int m = 0; m < 4; ++m) {
            int r = wr * 64 + m * 16 + (l & 15);
            a[m] = *(const short8v*)&At[(r * 128 + kb) ^ ((r & 15) << 3)];
        }
#pragma unroll
        for (int nn = 0; nn < 4; ++nn) {
            int c = wc * 64 + nn * 16 + (l & 15);
            b[nn] = *(const short8v*)&Bt[(c * 128 + kb) ^ ((c & 15) << 3)];
        }
#pragma unroll
        for (int m = 0; m < 4; ++m)
#pragma unroll
            for (int nn = 0; nn < 4; ++nn)
                acc[m][nn] = __builtin_amdgcn_mfma_f32_16x16x32_bf16(
                    a[m], b[nn], acc[m][nn], 0, 0, 0);
    }

    if (col0 < 256) {
        const float* bp = b2l;
        int cb = col0;
#pragma unroll
        for (int nn = 0; nn < 4; ++nn) {
            int colc = cb + wc * 64 + nn * 16 + (l & 15);
            float bv = bp[colc];
#pragma unroll
            for (int m = 0; m < 4; ++m) {
                int rbase = row0 + wr * 64 + m * 16 + ((l >> 4) << 2);
#pragma unroll
                for (int r = 0; r < 4; ++r) {
                    int row = rbase + r;
                    float val = acc[m][nn][r] + bv;
                    float other = __shfl_xor(val, 1);
                    if (!(l & 1) && row < n)
                        *(unsigned short*)(xl2 + (size_t)row * 256 + colc) =
                            f2fp8x2(val, other);
                }
            }
        }
    } else {
        const float* bp = b2r;
        int cb = col0 - 256;
#pragma unroll
        for (int nn = 0; nn < 4; ++nn) {
            int colc = cb + wc * 64 + nn * 16 + (l & 15);
            float bv = bp[colc];
#pragma unroll
            for (int m = 0; m < 4; ++m) {
                int rbase = row0 + wr * 64 + m * 16 + ((l >> 4) << 2);
#pragma unroll
                for (int r = 0; r < 4; ++r) {
                    int row = rbase + r;
                    float val = acc[m][nn][r] + bv;
                    float other = __shfl_xor(val, 1);
                    if (!(l & 1) && row < n)
                        *(unsigned*)(xr2 + (size_t)row * 256 + colc) =
                            u32_from_h2(pkrtz(val, other));
                }
            }
        }
    }
}

// ============ layer-1 aggregation: SGPR rows, packed-DPP reduce ============
__global__ __launch_bounds__(256) void k_agg1(
        const unsigned char* __restrict__ xl8, const unsigned short* __restrict__ xr16,
        const float* __restrict__ att, const float* __restrict__ bias,
        const int* __restrict__ rp, const int* __restrict__ deg,
        const int* __restrict__ eord, const int* __restrict__ ord,
        unsigned short* __restrict__ h1b, int n) {
    int t = threadIdx.x;
    int node0 = blockIdx.x * 4 + (t >> 6);
    int l = t & 63;
    bool valid = node0 < n;
    int node = rfl(ord[valid ? node0 : n - 1]);
    half2v xr01 = h2_from_u32(((const unsigned*)xr16)[(size_t)node * 64 + l]);
    float2 av = *(const float2*)(att + 2 * l);
    half2v av01 = pkrtz(av.x * LOG2E, av.y * LOG2E);
    half2v slp = pkrtz(SLOPE, SLOPE);
    int start = rfl(rp[node]);
    int cnt   = valid ? deg[node] : 0;
    cnt = rfl(cnt);
    const unsigned short* xlp = (const unsigned short*)xl8;  // row = 64 ushorts
    float d = 0.f;
    half2v a01 = pkrtz(0.f, 0.f);
    int cnt4 = cnt & ~3;
    unsigned g0, g1, g2, g3;
    int s0, s1, s2, s3;
    if (cnt4 > 0) {
        int4 iv = *(const int4*)(eord + start);
        s0 = rfl(iv.x); s1 = rfl(iv.y); s2 = rfl(iv.z); s3 = rfl(iv.w);
        g0 = xlp[(unsigned)(s0 << 6) + l]; g1 = xlp[(unsigned)(s1 << 6) + l];
        g2 = xlp[(unsigned)(s2 << 6) + l]; g3 = xlp[(unsigned)(s3 << 6) + l];
    }
    for (int j = 0; j < cnt4; j += 4) {
        unsigned c0 = g0, c1 = g1, c2 = g2, c3 = g3;
        int jn = j + 4;
        if (jn < cnt4) {
            int4 iv = *(const int4*)(eord + start + jn);
            s0 = rfl(iv.x); s1 = rfl(iv.y); s2 = rfl(iv.z); s3 = rfl(iv.w);
            g0 = xlp[(unsigned)(s0 << 6) + l]; g1 = xlp[(unsigned)(s1 << 6) + l];
            g2 = xlp[(unsigned)(s2 << 6) + l]; g3 = xlp[(unsigned)(s3 << 6) + l];
        }
        half2v x0 = fp8x2_to_h2<false>(c0), x1 = fp8x2_to_h2<false>(c1);
        half2v x2 = fp8x2_to_h2<false>(c2), x3 = fp8x2_to_h2<false>(c3);
        half2v s;
        float lg0, lg1, lg2, lg3;
        s = x0 + xr01; s = __builtin_elementwise_max(s, s * slp); lg0 = fdot2(av01, s, 0.f);
        s = x1 + xr01; s = __builtin_elementwise_max(s, s * slp); lg1 = fdot2(av01, s, 0.f);
        s = x2 + xr01; s = __builtin_elementwise_max(s, s * slp); lg2 = fdot2(av01, s, 0.f);
        s = x3 + xr01; s = __builtin_elementwise_max(s, s * slp); lg3 = fdot2(av01, s, 0.f);
        half2v l01 = dpp_sum16_h2(pkrtz(lg0, lg1));
        half2v l23 = dpp_sum16_h2(pkrtz(lg2, lg3));
        float e0 = exp2f((float)l01.x), e1 = exp2f((float)l01.y);
        float e2 = exp2f((float)l23.x), e3 = exp2f((float)l23.y);
        d += (e0 + e1) + (e2 + e3);
        a01 += pkrtz(e0, e0) * x0;
        a01 += pkrtz(e1, e1) * x1;
        a01 += pkrtz(e2, e2) * x2;
        a01 += pkrtz(e3, e3) * x3;
    }
    for (int j = cnt4; j < cnt; ++j) {
        int sj = rfl(eord[start + j]);
        half2v x0 = fp8x2_to_h2<false>((unsigned)xlp[(unsigned)(sj << 6) + l]);
        half2v s0v = x0 + xr01;
        s0v = __builtin_elementwise_max(s0v, s0v * slp);
        float lg0 = fdot2(av01, s0v, 0.f);
        lg0 = dpp_sum16(lg0);
        float e0 = exp2f(lg0);
        d += e0;
        a01 += pkrtz(e0, e0) * x0;
    }
    if (valid) {
        float inv = 1.f / d;
        float o0 = fmaxf((float)a01.x * inv + bias[2 * l + 0], 0.f);
        float o1 = fmaxf((float)a01.y * inv + bias[2 * l + 1], 0.f);
        ((unsigned*)h1b)[(size_t)node * 64 + l] =
            ((unsigned)f2bf(o1) << 16) | f2bf(o0);
    }
}

// ============ layer-2 aggregation + head: SGPR rows, packed-DPP reduce =====
__global__ __launch_bounds__(256) void k_agg2(
        const unsigned char* __restrict__ xl8, const unsigned short* __restrict__ xr16,
        const float* __restrict__ att, const float* __restrict__ b2,
        const float* __restrict__ W3, const float* __restrict__ b3,
        const int* __restrict__ rp, const int* __restrict__ deg,
        const int* __restrict__ eord, const int* __restrict__ ord,
        float* __restrict__ out, int n) {
    int t = threadIdx.x;
    int node0 = blockIdx.x * 4 + (t >> 6);
    int l = t & 63;
    bool valid = node0 < n;
    int node = rfl(ord[valid ? node0 : n - 1]);
    uint2 xru = ((const uint2*)xr16)[(size_t)node * 64 + l];
    half2v xr01 = h2_from_u32(xru.x), xr23 = h2_from_u32(xru.y);
    float4 av = *(const float4*)(att + 4 * l);
    half2v av01 = pkrtz(av.x * LOG2E, av.y * LOG2E);
    half2v av23 = pkrtz(av.z * LOG2E, av.w * LOG2E);
    half2v slp = pkrtz(SLOPE, SLOPE);
    int start = rfl(rp[node]);
    int cnt   = valid ? deg[node] : 0;
    cnt = rfl(cnt);
    const unsigned* xlp = (const unsigned*)xl8;   // row = 64 uints (256 fp8)
    float d = 0.f;
    half2v a01 = pkrtz(0.f, 0.f), a23 = pkrtz(0.f, 0.f);
    int cnt4 = cnt & ~3;
    unsigned g0, g1, g2, g3;
    int s0, s1, s2, s3;
    if (cnt4 > 0) {
        int4 iv = *(const int4*)(eord + start);
        s0 = rfl(iv.x); s1 = rfl(iv.y); s2 = rfl(iv.z); s3 = rfl(iv.w);
        g0 = xlp[(unsigned)(s0 << 6) + l]; g1 = xlp[(unsigned)(s1 << 6) + l];
        g2 = xlp[(unsigned)(s2 << 6) + l]; g3 = xlp[(unsigned)(s3 << 6) + l];
    }
    for (int j = 0; j < cnt4; j += 4) {
        unsigned c0 = g0, c1 = g1, c2 = g2, c3 = g3;
        int jn = j + 4;
        if (jn < cnt4) {
            int4 iv = *(const int4*)(eord + start + jn);
            s0 = rfl(iv.x); s1 = rfl(iv.y); s2 = rfl(iv.z); s3 = rfl(iv.w);
            g0 = xlp[(unsigned)(s0 << 6) + l]; g1 = xlp[(unsigned)(s1 << 6) + l];
            g2 = xlp[(unsigned)(s2 << 6) + l]; g3 = xlp[(unsigned)(s3 << 6) + l];
        }
        half2v x0lo = fp8x2_to_h2<false>(c0), x0hi = fp8x2_to_h2<true>(c0);
        half2v x1lo = fp8x2_to_h2<false>(c1), x1hi = fp8x2_to_h2<true>(c1);
        half2v x2lo = fp8x2_to_h2<false>(c2), x2hi = fp8x2_to_h2<true>(c2);
        half2v x3lo = fp8x2_to_h2<false>(c3), x3hi = fp8x2_to_h2<true>(c3);
        half2v s;
        float lg0, lg1, lg2, lg3;
        s = x0lo + xr01; s = __builtin_elementwise_max(s, s * slp); lg0 = fdot2(av01, s, 0.f);
        s = x0hi + xr23; s = __builtin_elementwise_max(s, s * slp); lg0 = fdot2(av23, s, lg0);
        s = x1lo + xr01; s = __builtin_elementwise_max(s, s * slp); lg1 = fdot2(av01, s, 0.f);
        s = x1hi + xr23; s = __builtin_elementwise_max(s, s * slp); lg1 = fdot2(av23, s, lg1);
        s = x2lo + xr01; s = __builtin_elementwise_max(s, s * slp); lg2 = fdot2(av01, s, 0.f);
        s = x2hi + xr23; s = __builtin_elementwise_max(s, s * slp); lg2 = fdot2(av23, s, lg2);
        s = x3lo + xr01; s = __builtin_elementwise_max(s, s * slp); lg3 = fdot2(av01, s, 0.f);
        s = x3hi + xr23; s = __builtin_elementwise_max(s, s * slp); lg3 = fdot2(av23, s, lg3);
        half2v l01 = dpp_sum16_h2(pkrtz(lg0, lg1));
        half2v l23 = dpp_sum16_h2(pkrtz(lg2, lg3));
        float e0 = exp2f((float)l01.x), e1 = exp2f((float)l01.y);
        float e2 = exp2f((float)l23.x), e3 = exp2f((float)l23.y);
        d += (e0 + e1) + (e2 + e3);
        half2v ep;
        ep = pkrtz(e0, e0); a01 += ep * x0lo; a23 += ep * x0hi;
        ep = pkrtz(e1, e1); a01 += ep * x1lo; a23 += ep * x1hi;
        ep = pkrtz(e2, e2); a01 += ep * x2lo; a23 += ep * x2hi;
        ep = pkrtz(e3, e3); a01 += ep * x3lo; a23 += ep * x3hi;
    }
    for (int j = cnt4; j < cnt; ++j) {
        int sj = rfl(eord[start + j]);
        unsigned p0 = xlp[(unsigned)(sj << 6) + l];
        half2v xlo = fp8x2_to_h2<false>(p0), xhi = fp8x2_to_h2<true>(p0);
        half2v s;
        float lg0;
        s = xlo + xr01; s = __builtin_elementwise_max(s, s * slp); lg0 = fdot2(av01, s, 0.f);
        s = xhi + xr23; s = __builtin_elementwise_max(s, s * slp); lg0 = fdot2(av23, s, lg0);
        lg0 = dpp_sum16(lg0);
        float e0 = exp2f(lg0);
        d += e0;
        half2v ep = pkrtz(e0, e0);
        a01 += ep * xlo; a23 += ep * xhi;
    }
    float inv = 1.f / d;
    float v0 = (float)a01.x * inv, v1 = (float)a01.y * inv;
    float v2 = (float)a23.x * inv, v3 = (float)a23.y * inv;
    v0 += __shfl_xor(v0, 16); v1 += __shfl_xor(v1, 16);
    v2 += __shfl_xor(v2, 16); v3 += __shfl_xor(v3, 16);
    v0 += __shfl_xor(v0, 32); v1 += __shfl_xor(v1, 32);
    v2 += __shfl_xor(v2, 32); v3 += __shfl_xor(v3, 32);
    int c0i = 4 * (l & 15);
    v0 = fmaxf(0.25f * v0 + b2[c0i + 0], 0.f);
    v1 = fmaxf(0.25f * v1 + b2[c0i + 1], 0.f);
    v2 = fmaxf(0.25f * v2 + b2[c0i + 2], 0.f);
    v3 = fmaxf(0.25f * v3 + b2[c0i + 3], 0.f);
    float p0, p1, p2, p3, p4;
    {
        const float* w0 = W3 + (c0i + 0) * 5;
        const float* w1 = W3 + (c0i + 1) * 5;
        const float* w2 = W3 + (c0i + 2) * 5;
        const float* w3 = W3 + (c0i + 3) * 5;
        p0 = v0 * w0[0] + v1 * w1[0] + v2 * w2[0] + v3 * w3[0];
        p1 = v0 * w0[1] + v1 * w1[1] + v2 * w2[1] + v3 * w3[1];
        p2 = v0 * w0[2] + v1 * w1[2] + v2 * w2[2] + v3 * w3[2];
        p3 = v0 * w0[3] + v1 * w1[3] + v2 * w2[3] + v3 * w3[3];
        p4 = v0 * w0[4] + v1 * w1[4] + v2 * w2[4] + v3 * w3[4];
    }
    p0 = dpp_sum16(p0); p1 = dpp_sum16(p1); p2 = dpp_sum16(p2);
    p3 = dpp_sum16(p3); p4 = dpp_sum16(p4);
    if (l == 0 && valid) {
        float* o = out + (size_t)node * 5;
        o[0] = 1.f / (1.f + __expf(-(p0 + b3[0])));
        o[1] = 1.f / (1.f + __expf(-(p1 + b3[1])));
        o[2] = 1.f / (1.f + __expf(-(p2 + b3[2])));
        o[3] = 1.f / (1.f + __expf(-(p3 + b3[3])));
        o[4] = 1.f / (1.f + __expf(-(p4 + b3[4])));
    }
}

extern "C" void kernel_launch(void* const* d_in, const int* in_sizes, int n_in,
                              void* d_out, int out_size, void* d_ws, size_t ws_size,
                              hipStream_t stream) {
    const float* x     = (const float*)d_in[0];
    const int*   ei    = (const int*)d_in[1];
    const float* lb    = (const float*)d_in[2];
    const float* ub    = (const float*)d_in[3];
    const float* W1l   = (const float*)d_in[4];
    const float* b1l   = (const float*)d_in[5];
    const float* W1r   = (const float*)d_in[6];
    const float* b1r   = (const float*)d_in[7];
    const float* att1  = (const float*)d_in[8];
    const float* bias1 = (const float*)d_in[9];
    const float* W2l   = (const float*)d_in[10];
    const float* b2l   = (const float*)d_in[11];
    const float* W2r   = (const float*)d_in[12];
    const float* b2r   = (const float*)d_in[13];
    const float* att2  = (const float*)d_in[14];
    const float* bias2 = (const float*)d_in[15];
    const float* W3    = (const float*)d_in[16];
    const float* b3    = (const float*)d_in[17];

    int n  = in_sizes[0] / CIN;
    int E  = in_sizes[1] / 2;
    int ET = E + n;

    char* ws = (char*)d_ws;
    size_t off = 0;
    auto alloc = [&](size_t nbytes) {
        void* p = ws + off;
        off += (nbytes + 255) & ~(size_t)255;
        return p;
    };
    unsigned char*  xl1 = (unsigned char*)alloc((size_t)n * D1);        // fp8
    unsigned short* xr1 = (unsigned short*)alloc((size_t)n * D1 * 2);   // f16
    unsigned short* h1b = (unsigned short*)alloc((size_t)n * D1 * 2);   // bf16
    unsigned char*  xl2 = (unsigned char*)alloc((size_t)n * D2);        // fp8
    unsigned short* xr2 = (unsigned short*)alloc((size_t)n * D2 * 2);   // f16
    unsigned short* W2t = (unsigned short*)alloc((size_t)512 * 128 * 2);
    int* deg  = (int*)alloc((size_t)n * 4 + 8192);  // pad: scan over-reads int4
    int* cur  = (int*)alloc((size_t)n * 4);
    int* rp   = (int*)alloc((size_t)n * 4);
    int* ord  = (int*)alloc((size_t)n * 4);
    int* eord = (int*)alloc((size_t)ET * 4 + 256);

    // ---- prep: lin1 + cvtW2 + zero deg (one launch) ----
    int B1 = (n + 15) / 16;
    int BZ = (n + 255) / 256;
    k_prep<<<B1 + 256 + BZ, 256, 0, stream>>>(
        x, lb, ub, W1l, b1l, W1r, b1r, xl1, xr1, W2l, W2r, W2t, deg, n, B1);

    // ---- CSR build + degree sort ----
    k_hist<<<(ET + 255) / 256, 256, 0, stream>>>(ei, E, ET, deg);
    k_scan_one<<<1, 1024, 0, stream>>>(deg, rp, cur, ord, n);
    k_fill<<<(ET + 255) / 256, 256, 0, stream>>>(ei, E, ET, rp, cur, eord);

    // ---- layer 1 aggregation ----
    k_agg1<<<(n + 3) / 4, 256, 0, stream>>>(xl1, xr1, att1, bias1, rp, deg,
                                            eord, ord, h1b, n);

    // ---- layer 2 ----
    dim3 g2((n + 127) / 128, 4);
    k_lin2_mfma<<<g2, 256, 0, stream>>>(h1b, W2t, b2l, b2r, xl2, xr2, n);
    k_agg2<<<(n + 3) / 4, 256, 0, stream>>>(xl2, xr2, att2, bias2, W3, b3,
                                            rp, deg, eord, ord, (float*)d_out, n);
}